// Round 11
// baseline (238.330 us; speedup 1.0000x reference)
//
#include <hip/hip_runtime.h>
#include <math.h>

#define NSIG   1023
#define BATCH  16
#define FT     1024          // F_BINS == T == 1024
#define KW     256           // truncated window taps, d in [-128, 127] (4 sigma)
#define RHALF  128
#define XPAD   1280          // 128 + 1023 + 127 (+2 pad)
#define HID    128

// ws layout (float offsets)
#define OFF_XCP  0u                       // 16*1280 = 20480
#define OFF_G    20480u                   // 256
#define OFF_HRAW 20736u                   // 2048  (fc1 accum, b-major: b*128+j)
#define OFF_TAB  22784u                   // bf16 hi/lo tables, 4 x 262144 u16
// u16 offsets within tab (f-major [f][256])
#define TAB_ECH  0u
#define TAB_ECL  262144u
#define TAB_ESH  524288u
#define TAB_ESL  786432u

typedef int    i32x4  __attribute__((ext_vector_type(4)));
typedef float  f32x4  __attribute__((ext_vector_type(4)));
typedef __bf16 bf16x8 __attribute__((ext_vector_type(8)));
typedef unsigned short u16;

static __device__ __forceinline__ unsigned bfbits(float v) {
    unsigned u = __builtin_bit_cast(unsigned, v);
    return (u + 0x7fffu + ((u >> 16) & 1u)) >> 16;   // RNE round to bf16
}

// ---------------- K0: per-batch mean removal into zero-padded buffer ----------
__global__ void k_prep(const float* __restrict__ x, float* __restrict__ ws) {
    int b = blockIdx.x;
    __shared__ float red[256];
    float s = 0.f;
    for (int i = threadIdx.x; i < NSIG; i += 256) s += x[b * NSIG + i];
    red[threadIdx.x] = s;
    __syncthreads();
    for (int o = 128; o > 0; o >>= 1) {
        if (threadIdx.x < o) red[threadIdx.x] += red[threadIdx.x + o];
        __syncthreads();
    }
    float mean = red[0] * (1.0f / NSIG);
    float* xcp = ws + OFF_XCP + b * XPAD;
    for (int i = threadIdx.x; i < XPAD; i += 256) {
        int n = i - RHALF;
        xcp[i] = (n >= 0 && n < NSIG) ? (x[b * NSIG + n] - mean) : 0.f;
    }
}

// ---------------- K1: hi/lo bf16 sincos tables, f-major [f][256] --------------
__global__ void k_tables(const float* __restrict__ lambd, float* __restrict__ ws) {
    int bid = blockIdx.x;
    if (bid == 1024) {
        float sigma = fabsf(lambd[0]);
        float inv2s2 = 0.5f / (sigma * sigma);
        for (int i = threadIdx.x; i < KW; i += 256) {
            float d = (float)(i - RHALF);
            ws[OFF_G + i] = expf(-d * d * inv2s2);
        }
        for (int i = threadIdx.x; i < 2048; i += 256) ws[OFF_HRAW + i] = 0.f;
        return;
    }
    int idx = bid * 256 + threadIdx.x;       // 0 .. 262143 = f*256 + k
    int f = idx >> 8, k = idx & 255;
    int d = k - RHALF;
    int p = f * d;                           // |p| <= 130944, fits int
    int m = p % 2046; if (m < 0) m += 2046;  // exact phase mod 2pi
    double ang = (double)m * (6.283185307179586476925286766559 / 2046.0);
    double sv, cv;
    sincos(ang, &sv, &cv);
    float cf = (float)cv, sf = (float)sv;
    u16* tab = (u16*)(ws + OFF_TAB);
    unsigned chb = bfbits(cf);
    float chf = __builtin_bit_cast(float, chb << 16);
    unsigned clb = bfbits(cf - chf);
    unsigned shb = bfbits(sf);
    float shf = __builtin_bit_cast(float, shb << 16);
    unsigned slb = bfbits(sf - shf);
    tab[TAB_ECH + idx] = (u16)chb;
    tab[TAB_ECL + idx] = (u16)clb;
    tab[TAB_ESH + idx] = (u16)shb;
    tab[TAB_ESL + idx] = (u16)slb;
}

// ---------------- K2: spectrogram MFMA, full-y-in-LDS, barrier-free loop ------
// (unchanged from R6/R7 — proven)
__global__ __launch_bounds__(512, 4) void k_spec(const float* __restrict__ ws,
                                                 float* __restrict__ out) {
    __shared__ u16 yH[64 * 256];   // 32 KB, swizzled [t][256]
    __shared__ u16 yL[64 * 256];   // 32 KB
    int t0 = blockIdx.x * 64, f0 = blockIdx.y * 128, b = blockIdx.z;
    int tid = threadIdx.x;
    int wave = tid >> 6, lane = tid & 63;
    int lo = lane & 15, hi4 = lane >> 4;
    const u16* tab = (const u16*)(ws + OFF_TAB);
    const float* xcp = ws + OFF_XCP + b * XPAD;
    const float* gw  = ws + OFF_G;

    #pragma unroll
    for (int i = 0; i < 4; i++) {
        int idx = tid + i * 512;             // 0..2047
        int t = idx >> 5, kg = idx & 31;
        int k = kg * 8;
        const float* xp = xcp + t0 + t + k;
        float4 g0 = *(const float4*)&gw[k];
        float4 g1 = *(const float4*)&gw[k + 4];
        float yv[8];
        yv[0] = xp[0] * g0.x; yv[1] = xp[1] * g0.y;
        yv[2] = xp[2] * g0.z; yv[3] = xp[3] * g0.w;
        yv[4] = xp[4] * g1.x; yv[5] = xp[5] * g1.y;
        yv[6] = xp[6] * g1.z; yv[7] = xp[7] * g1.w;
        unsigned hb[8], lb[8];
        #pragma unroll
        for (int j = 0; j < 8; j++) {
            unsigned u = __builtin_bit_cast(unsigned, yv[j]);
            unsigned h = (u + 0x7fffu + ((u >> 16) & 1u)) & 0xffff0000u;
            float hf = __builtin_bit_cast(float, h);
            hb[j] = h >> 16;
            lb[j] = bfbits(yv[j] - hf);
        }
        i32x4 ph, pl;
        ph.x = (int)(hb[0] | (hb[1] << 16)); ph.y = (int)(hb[2] | (hb[3] << 16));
        ph.z = (int)(hb[4] | (hb[5] << 16)); ph.w = (int)(hb[6] | (hb[7] << 16));
        pl.x = (int)(lb[0] | (lb[1] << 16)); pl.y = (int)(lb[2] | (lb[3] << 16));
        pl.z = (int)(lb[4] | (lb[5] << 16)); pl.w = (int)(lb[6] | (lb[7] << 16));
        int wb = ((t * 512 + kg * 16) ^ ((t & 7) << 4));
        *(i32x4*)((char*)yH + wb) = ph;
        *(i32x4*)((char*)yL + wb) = pl;
    }
    __syncthreads();

    size_t arow = (size_t)(f0 + wave * 16 + lo) * 256 + hi4 * 8;
    const u16* pech = tab + TAB_ECH + arow;
    const u16* pecl = tab + TAB_ECL + arow;
    const u16* pesh = tab + TAB_ESH + arow;
    const u16* pesl = tab + TAB_ESL + arow;

    f32x4 reA[4], imA[4];
    #pragma unroll
    for (int i = 0; i < 4; i++) {
        reA[i] = (f32x4){0.f, 0.f, 0.f, 0.f};
        imA[i] = (f32x4){0.f, 0.f, 0.f, 0.f};
    }

    #pragma unroll 2
    for (int c = 0; c < 8; c++) {
        i32x4 ech = *(const i32x4*)(pech + c * 32);
        i32x4 ecl = *(const i32x4*)(pecl + c * 32);
        i32x4 esh = *(const i32x4*)(pesh + c * 32);
        i32x4 esl = *(const i32x4*)(pesl + c * 32);
        #pragma unroll
        for (int tt = 0; tt < 4; tt++) {
            int tr = tt * 16 + lo;
            int rb = ((tr * 512 + c * 64 + hi4 * 16) ^ ((tr & 7) << 4));
            i32x4 yh = *(const i32x4*)((const char*)yH + rb);
            i32x4 yl = *(const i32x4*)((const char*)yL + rb);
            asm("v_mfma_f32_16x16x32_bf16 %0, %1, %2, %0" : "+v"(reA[tt]) : "v"(ech), "v"(yh));
            asm("v_mfma_f32_16x16x32_bf16 %0, %1, %2, %0" : "+v"(imA[tt]) : "v"(esh), "v"(yh));
            asm("v_mfma_f32_16x16x32_bf16 %0, %1, %2, %0" : "+v"(reA[tt]) : "v"(ech), "v"(yl));
            asm("v_mfma_f32_16x16x32_bf16 %0, %1, %2, %0" : "+v"(imA[tt]) : "v"(esh), "v"(yl));
            asm("v_mfma_f32_16x16x32_bf16 %0, %1, %2, %0" : "+v"(reA[tt]) : "v"(ecl), "v"(yh));
            asm("v_mfma_f32_16x16x32_bf16 %0, %1, %2, %0" : "+v"(imA[tt]) : "v"(esl), "v"(yh));
        }
    }
    asm volatile("s_nop 7\n\ts_nop 7");   // MFMA->VALU read hazard guard

    float* dS = out + 160;
    #pragma unroll
    for (int tt = 0; tt < 4; tt++) {
        #pragma unroll
        for (int r = 0; r < 4; r++) {
            int f = f0 + wave * 16 + hi4 * 4 + r;
            float re = reA[tt][r], im = imA[tt][r];
            dS[((size_t)b << 20) + (size_t)f * 1024 + t0 + tt * 16 + lo] = re * re + im * im;
        }
    }
}

// ---------------- K3: fc1 — LDS-staged W1, 512 B/row DRAM chunks --------------
// h[b,j] = sum_i S[b,i]*W1[j,i]. 4096 blocks x 4 waves: block = (ksg, jtg);
// wave w handles k-stripe ks = ksg*4+w for j-tile jtg (16 j). Per step, the
// staged tile is [16 rows][128 k] f32 = 8 KB: each row fetched as 512 B
// CONTIGUOUS (vs 128 B before) -> 4x DRAM page locality. 4 steps/stripe,
// double-buffered private LDS, counted vmcnt(8), no barriers in the loop.
// LDS layout row-major [16][512 B] with XOR swizzle byte ^= (row&7)<<4
// (pre-applied on the global source column; involution on read).
static __device__ __forceinline__ bf16x8 packc4(float4 a, float4 b) {
    bf16x8 r;
    r[0] = (__bf16)a.x; r[1] = (__bf16)a.y; r[2] = (__bf16)a.z; r[3] = (__bf16)a.w;
    r[4] = (__bf16)b.x; r[5] = (__bf16)b.y; r[6] = (__bf16)b.z; r[7] = (__bf16)b.w;
    return r;
}
static __device__ __forceinline__ bf16x8 packcv(f32x4 a, f32x4 b) {
    bf16x8 r;
    r[0] = (__bf16)a.x; r[1] = (__bf16)a.y; r[2] = (__bf16)a.z; r[3] = (__bf16)a.w;
    r[4] = (__bf16)b.x; r[5] = (__bf16)b.y; r[6] = (__bf16)b.z; r[7] = (__bf16)b.w;
    return r;
}

// stage [16 rows][128 floats]: instr i covers rows {2i, 2i+1}, 32 lanes per row
// reading 512 B contiguous (swizzle-permuted in 16 B units within each 128 B).
static __device__ __forceinline__ void stageW(const float* base, float* dst,
                                              int rowLane, int colb0) {
    #pragma unroll
    for (int i = 0; i < 8; i++) {
        int sw = ((2 * (i & 3)) + rowLane) << 4;
        const float* src = base + (size_t)(2 * i + rowLane) * (1u << 20)
                         + ((colb0 ^ sw) >> 2);
        __builtin_amdgcn_global_load_lds(
            (const __attribute__((address_space(1))) void*)src,
            (__attribute__((address_space(3))) void*)((char*)dst + i * 1024),
            16, 0, 0);
    }
}

__global__ __launch_bounds__(256, 2) void k_fc1(const float* __restrict__ S,
                                                const float* __restrict__ W1,
                                                float* __restrict__ hraw) {
    __shared__ float Wl[4][2][2048];   // [wave][buf][8 KB] = 64 KB
    int tid = threadIdx.x;
    int wave = tid >> 6, lane = tid & 63;
    int jtg = blockIdx.x & 7;                    // j-tile 0..7 (16 j each)
    int ksg = blockIdx.x >> 3;                   // 0..511
    int ks  = (ksg << 2) | wave;                 // 0..2047 k-stripe
    int bq = lane >> 4, lo = lane & 15;
    int rowLane = lane >> 5;                     // 0..1
    int colb0 = (lane & 31) << 4;                // 0..496 bytes within 512 B row
    int sw = (lo & 7) << 4;

    const float* Sp = S + (size_t)lo * (1u << 20) + (size_t)ks * 512 + bq * 8;
    const float* Wb = W1 + (size_t)(jtg * 16) * (1u << 20) + (size_t)ks * 512;
    float* buf0 = &Wl[wave][0][0];
    float* buf1 = &Wl[wave][1][0];

    f32x4 acc = {0.f, 0.f, 0.f, 0.f};

    stageW(Wb, buf0, rowLane, colb0);

    #pragma unroll
    for (int s = 0; s < 4; s++) {
        float4 sA0[4], sA1[4];
        #pragma unroll
        for (int c = 0; c < 4; c++) {
            const float* sp = Sp + s * 128 + c * 32;
            sA0[c] = *(const float4*)(sp);
            sA1[c] = *(const float4*)(sp + 4);
        }
        if (s < 3) {
            stageW(Wb + (s + 1) * 128, (s & 1) ? buf0 : buf1, rowLane, colb0);
            asm volatile("s_waitcnt vmcnt(8)" ::: "memory");
        } else {
            asm volatile("s_waitcnt vmcnt(0)" ::: "memory");
        }
        const char* wb = (const char*)((s & 1) ? buf1 : buf0);
        #pragma unroll
        for (int c = 0; c < 4; c++) {
            f32x4 w0 = *(const f32x4*)(wb + lo * 512 + ((c * 128 + bq * 32) ^ sw));
            f32x4 w1 = *(const f32x4*)(wb + lo * 512 + ((c * 128 + bq * 32 + 16) ^ sw));
            acc = __builtin_amdgcn_mfma_f32_16x16x32_bf16(packc4(sA0[c], sA1[c]),
                                                          packcv(w0, w1), acc, 0, 0, 0);
        }
    }

    // cross-wave reduce (4 waves share (b,j) set, differ in ks) -> 256 atomics
    float* red = &Wl[wave][0][0];
    #pragma unroll
    for (int r = 0; r < 4; r++) red[(bq * 4 + r) * 16 + lo] = acc[r];
    __syncthreads();
    float v = Wl[0][0][tid & 255] + Wl[1][0][tid & 255]
            + Wl[2][0][tid & 255] + Wl[3][0][tid & 255];
    atomicAdd(&hraw[(tid >> 4) * HID + jtg * 16 + (tid & 15)], v);
}

// ---------------- K4: bias+relu+fc2 head --------------------------------------
__global__ void k_head(const float* __restrict__ hraw, const float* __restrict__ b1,
                       const float* __restrict__ W2, const float* __restrict__ b2,
                       float* __restrict__ out) {
    __shared__ float hl[2048];
    int tid = threadIdx.x;
    for (int p = tid; p < 2048; p += 256) {
        float hv = hraw[p] + b1[p & 127];
        hl[p] = hv > 0.f ? hv : 0.f;
    }
    __syncthreads();
    if (tid < 160) {
        int b = tid / 10, c = tid - b * 10;
        float s = b2[c];
        for (int j = 0; j < 128; j++) s += hl[b * 128 + j] * W2[c * 128 + j];
        out[b * 10 + c] = s;
    }
}

extern "C" void kernel_launch(void* const* d_in, const int* in_sizes, int n_in,
                              void* d_out, int out_size, void* d_ws, size_t ws_size,
                              hipStream_t stream) {
    const float* x     = (const float*)d_in[0];
    const float* lambd = (const float*)d_in[1];
    const float* W1    = (const float*)d_in[2];
    const float* b1    = (const float*)d_in[3];
    const float* W2    = (const float*)d_in[4];
    const float* b2    = (const float*)d_in[5];
    float* out = (float*)d_out;
    float* ws  = (float*)d_ws;

    hipLaunchKernelGGL(k_prep,   dim3(16),         dim3(256), 0, stream, x, ws);
    hipLaunchKernelGGL(k_tables, dim3(1025),       dim3(256), 0, stream, lambd, ws);
    hipLaunchKernelGGL(k_spec,   dim3(16, 8, 16),  dim3(512), 0, stream, ws, out);
    hipLaunchKernelGGL(k_fc1,    dim3(4096),       dim3(256), 0, stream,
                       out + 160, W1, ws + OFF_HRAW);
    hipLaunchKernelGGL(k_head,   dim3(1),          dim3(256), 0, stream,
                       ws + OFF_HRAW, b1, W2, b2, out);
}

// Round 12
// 233.721 us; speedup vs baseline: 1.0197x; 1.0197x over previous
//
#include <hip/hip_runtime.h>
#include <math.h>

#define NSIG   1023
#define BATCH  16
#define FT     1024          // F_BINS == T == 1024
#define KW     256           // truncated window taps, d in [-128, 127] (4 sigma)
#define RHALF  128
#define XPAD   1280          // 128 + 1023 + 127 (+2 pad)
#define HID    128

// ws layout (float offsets)
#define OFF_XCP  0u                       // 16*1280 = 20480
#define OFF_G    20480u                   // 256
#define OFF_HRAW 20736u                   // 2048  (fc1 accum, b-major: b*128+j)
#define OFF_TAB  22784u                   // bf16 hi/lo tables, 4 x 262144 u16
// u16 offsets within tab (f-major [f][256])
#define TAB_ECH  0u
#define TAB_ECL  262144u
#define TAB_ESH  524288u
#define TAB_ESL  786432u

typedef int    i32x4  __attribute__((ext_vector_type(4)));
typedef float  f32x4  __attribute__((ext_vector_type(4)));
typedef __bf16 bf16x8 __attribute__((ext_vector_type(8)));
typedef unsigned short u16;

static __device__ __forceinline__ unsigned bfbits(float v) {
    unsigned u = __builtin_bit_cast(unsigned, v);
    return (u + 0x7fffu + ((u >> 16) & 1u)) >> 16;   // RNE round to bf16
}

// ---------------- K0: per-batch mean removal into zero-padded buffer ----------
__global__ void k_prep(const float* __restrict__ x, float* __restrict__ ws) {
    int b = blockIdx.x;
    __shared__ float red[256];
    float s = 0.f;
    for (int i = threadIdx.x; i < NSIG; i += 256) s += x[b * NSIG + i];
    red[threadIdx.x] = s;
    __syncthreads();
    for (int o = 128; o > 0; o >>= 1) {
        if (threadIdx.x < o) red[threadIdx.x] += red[threadIdx.x + o];
        __syncthreads();
    }
    float mean = red[0] * (1.0f / NSIG);
    float* xcp = ws + OFF_XCP + b * XPAD;
    for (int i = threadIdx.x; i < XPAD; i += 256) {
        int n = i - RHALF;
        xcp[i] = (n >= 0 && n < NSIG) ? (x[b * NSIG + n] - mean) : 0.f;
    }
}

// ---------------- K1: hi/lo bf16 sincos tables, f-major [f][256] --------------
__global__ void k_tables(const float* __restrict__ lambd, float* __restrict__ ws) {
    int bid = blockIdx.x;
    if (bid == 1024) {
        float sigma = fabsf(lambd[0]);
        float inv2s2 = 0.5f / (sigma * sigma);
        for (int i = threadIdx.x; i < KW; i += 256) {
            float d = (float)(i - RHALF);
            ws[OFF_G + i] = expf(-d * d * inv2s2);
        }
        for (int i = threadIdx.x; i < 2048; i += 256) ws[OFF_HRAW + i] = 0.f;
        return;
    }
    int idx = bid * 256 + threadIdx.x;       // 0 .. 262143 = f*256 + k
    int f = idx >> 8, k = idx & 255;
    int d = k - RHALF;
    int p = f * d;                           // |p| <= 130944, fits int
    int m = p % 2046; if (m < 0) m += 2046;  // exact phase mod 2pi
    double ang = (double)m * (6.283185307179586476925286766559 / 2046.0);
    double sv, cv;
    sincos(ang, &sv, &cv);
    float cf = (float)cv, sf = (float)sv;
    u16* tab = (u16*)(ws + OFF_TAB);
    unsigned chb = bfbits(cf);
    float chf = __builtin_bit_cast(float, chb << 16);
    unsigned clb = bfbits(cf - chf);
    unsigned shb = bfbits(sf);
    float shf = __builtin_bit_cast(float, shb << 16);
    unsigned slb = bfbits(sf - shf);
    tab[TAB_ECH + idx] = (u16)chb;
    tab[TAB_ECL + idx] = (u16)clb;
    tab[TAB_ESH + idx] = (u16)shb;
    tab[TAB_ESL + idx] = (u16)slb;
}

// ---------------- K2: spectrogram MFMA, full-y-in-LDS, barrier-free loop ------
// (unchanged from R6/R7 — proven)
__global__ __launch_bounds__(512, 4) void k_spec(const float* __restrict__ ws,
                                                 float* __restrict__ out) {
    __shared__ u16 yH[64 * 256];   // 32 KB, swizzled [t][256]
    __shared__ u16 yL[64 * 256];   // 32 KB
    int t0 = blockIdx.x * 64, f0 = blockIdx.y * 128, b = blockIdx.z;
    int tid = threadIdx.x;
    int wave = tid >> 6, lane = tid & 63;
    int lo = lane & 15, hi4 = lane >> 4;
    const u16* tab = (const u16*)(ws + OFF_TAB);
    const float* xcp = ws + OFF_XCP + b * XPAD;
    const float* gw  = ws + OFF_G;

    #pragma unroll
    for (int i = 0; i < 4; i++) {
        int idx = tid + i * 512;             // 0..2047
        int t = idx >> 5, kg = idx & 31;
        int k = kg * 8;
        const float* xp = xcp + t0 + t + k;
        float4 g0 = *(const float4*)&gw[k];
        float4 g1 = *(const float4*)&gw[k + 4];
        float yv[8];
        yv[0] = xp[0] * g0.x; yv[1] = xp[1] * g0.y;
        yv[2] = xp[2] * g0.z; yv[3] = xp[3] * g0.w;
        yv[4] = xp[4] * g1.x; yv[5] = xp[5] * g1.y;
        yv[6] = xp[6] * g1.z; yv[7] = xp[7] * g1.w;
        unsigned hb[8], lb[8];
        #pragma unroll
        for (int j = 0; j < 8; j++) {
            unsigned u = __builtin_bit_cast(unsigned, yv[j]);
            unsigned h = (u + 0x7fffu + ((u >> 16) & 1u)) & 0xffff0000u;
            float hf = __builtin_bit_cast(float, h);
            hb[j] = h >> 16;
            lb[j] = bfbits(yv[j] - hf);
        }
        i32x4 ph, pl;
        ph.x = (int)(hb[0] | (hb[1] << 16)); ph.y = (int)(hb[2] | (hb[3] << 16));
        ph.z = (int)(hb[4] | (hb[5] << 16)); ph.w = (int)(hb[6] | (hb[7] << 16));
        pl.x = (int)(lb[0] | (lb[1] << 16)); pl.y = (int)(lb[2] | (lb[3] << 16));
        pl.z = (int)(lb[4] | (lb[5] << 16)); pl.w = (int)(lb[6] | (lb[7] << 16));
        int wb = ((t * 512 + kg * 16) ^ ((t & 7) << 4));
        *(i32x4*)((char*)yH + wb) = ph;
        *(i32x4*)((char*)yL + wb) = pl;
    }
    __syncthreads();

    size_t arow = (size_t)(f0 + wave * 16 + lo) * 256 + hi4 * 8;
    const u16* pech = tab + TAB_ECH + arow;
    const u16* pecl = tab + TAB_ECL + arow;
    const u16* pesh = tab + TAB_ESH + arow;
    const u16* pesl = tab + TAB_ESL + arow;

    f32x4 reA[4], imA[4];
    #pragma unroll
    for (int i = 0; i < 4; i++) {
        reA[i] = (f32x4){0.f, 0.f, 0.f, 0.f};
        imA[i] = (f32x4){0.f, 0.f, 0.f, 0.f};
    }

    #pragma unroll 2
    for (int c = 0; c < 8; c++) {
        i32x4 ech = *(const i32x4*)(pech + c * 32);
        i32x4 ecl = *(const i32x4*)(pecl + c * 32);
        i32x4 esh = *(const i32x4*)(pesh + c * 32);
        i32x4 esl = *(const i32x4*)(pesl + c * 32);
        #pragma unroll
        for (int tt = 0; tt < 4; tt++) {
            int tr = tt * 16 + lo;
            int rb = ((tr * 512 + c * 64 + hi4 * 16) ^ ((tr & 7) << 4));
            i32x4 yh = *(const i32x4*)((const char*)yH + rb);
            i32x4 yl = *(const i32x4*)((const char*)yL + rb);
            asm("v_mfma_f32_16x16x32_bf16 %0, %1, %2, %0" : "+v"(reA[tt]) : "v"(ech), "v"(yh));
            asm("v_mfma_f32_16x16x32_bf16 %0, %1, %2, %0" : "+v"(imA[tt]) : "v"(esh), "v"(yh));
            asm("v_mfma_f32_16x16x32_bf16 %0, %1, %2, %0" : "+v"(reA[tt]) : "v"(ech), "v"(yl));
            asm("v_mfma_f32_16x16x32_bf16 %0, %1, %2, %0" : "+v"(imA[tt]) : "v"(esl), "v"(yl));
            asm("v_mfma_f32_16x16x32_bf16 %0, %1, %2, %0" : "+v"(reA[tt]) : "v"(ecl), "v"(yh));
            asm("v_mfma_f32_16x16x32_bf16 %0, %1, %2, %0" : "+v"(imA[tt]) : "v"(esl), "v"(yh));
        }
    }
    asm volatile("s_nop 7\n\ts_nop 7");   // MFMA->VALU read hazard guard

    float* dS = out + 160;
    #pragma unroll
    for (int tt = 0; tt < 4; tt++) {
        #pragma unroll
        for (int r = 0; r < 4; r++) {
            int f = f0 + wave * 16 + hi4 * 4 + r;
            float re = reA[tt][r], im = imA[tt][r];
            dS[((size_t)b << 20) + (size_t)f * 1024 + t0 + tt * 16 + lo] = re * re + im * im;
        }
    }
}

// ---------------- K3: fc1 — block-shared staged W1, single S read -------------
// h[b,j] = sum_i S[b,i]*W1[j,i]. 512 blocks; block owns contiguous k-range of
// 2048 for ALL 128 j -> S read exactly once grid-wide (64 MB). Per 64-k chunk
// the 4 waves cooperatively stage W[128 j][64 k] f32 (32 KB): each instruction
// fetches 4 rows x 256 B contiguous; consecutive chunks advance rows
// contiguously (page-friendly, R11-proven). Double-buffered 64 KB LDS ->
// 2 blocks/CU; 2-phase {stage-next || compute} with __syncthreads (implicit
// drain after compute; co-resident block covers the gap). XOR swizzle
// colb ^= (j&7)<<4 pre-applied on the global source (linear LDS dest).
// Waves own disjoint j-tiles (w*2, w*2+1) -> no cross-wave reduce.
static __device__ __forceinline__ bf16x8 packc4(float4 a, float4 b) {
    bf16x8 r;
    r[0] = (__bf16)a.x; r[1] = (__bf16)a.y; r[2] = (__bf16)a.z; r[3] = (__bf16)a.w;
    r[4] = (__bf16)b.x; r[5] = (__bf16)b.y; r[6] = (__bf16)b.z; r[7] = (__bf16)b.w;
    return r;
}
static __device__ __forceinline__ bf16x8 packcv(f32x4 a, f32x4 b) {
    bf16x8 r;
    r[0] = (__bf16)a.x; r[1] = (__bf16)a.y; r[2] = (__bf16)a.z; r[3] = (__bf16)a.w;
    r[4] = (__bf16)b.x; r[5] = (__bf16)b.y; r[6] = (__bf16)b.z; r[7] = (__bf16)b.w;
    return r;
}

__global__ __launch_bounds__(256, 2) void k_fc1(const float* __restrict__ S,
                                                const float* __restrict__ W1,
                                                float* __restrict__ hraw) {
    __shared__ float Wl[2][8192];   // 2 x 32 KB: [buf][128 rows x 64 floats]
    int tid = threadIdx.x;
    int wave = tid >> 6, lane = tid & 63;
    int bq = lane >> 4, lo = lane & 15;
    size_t kb = (size_t)blockIdx.x * 2048;

    // staging geometry: instr i stages rows w*32+i*4 .. +3, 256 B each
    int srow = lane >> 4;                        // 0..3 row within quad
    int scolb = (lane & 15) << 4;                // 16 B col within 256 B row

    const float* Sp = S + ((size_t)lo << 20) + kb + bq * 8;

    f32x4 acc0 = {0.f,0.f,0.f,0.f}, acc1 = acc0;

    // prologue: stage chunk 0 into buf 0
    #pragma unroll
    for (int i = 0; i < 8; i++) {
        int j = wave * 32 + i * 4 + srow;
        int colb = scolb ^ ((j & 7) << 4);
        const float* src = W1 + ((size_t)j << 20) + kb + (colb >> 2);
        __builtin_amdgcn_global_load_lds(
            (const __attribute__((address_space(1))) void*)src,
            (__attribute__((address_space(3))) void*)
                ((char*)&Wl[0][0] + (wave * 32 + i * 4) * 256),
            16, 0, 0);
    }
    __syncthreads();

    int j0 = (wave * 2) * 16 + lo;       // B-row for tile 0
    int j1 = (wave * 2 + 1) * 16 + lo;   // B-row for tile 1
    int sw0 = (j0 & 7) << 4, sw1 = (j1 & 7) << 4;

    for (int c = 0; c < 32; c++) {
        if (c < 31) {
            float* dbuf = (c & 1) ? &Wl[0][0] : &Wl[1][0];
            #pragma unroll
            for (int i = 0; i < 8; i++) {
                int j = wave * 32 + i * 4 + srow;
                int colb = scolb ^ ((j & 7) << 4);
                const float* src = W1 + ((size_t)j << 20) + kb + (c + 1) * 64 + (colb >> 2);
                __builtin_amdgcn_global_load_lds(
                    (const __attribute__((address_space(1))) void*)src,
                    (__attribute__((address_space(3))) void*)
                        ((char*)dbuf + (wave * 32 + i * 4) * 256),
                    16, 0, 0);
            }
        }
        const char* wb = (const char*)((c & 1) ? &Wl[1][0] : &Wl[0][0]);
        #pragma unroll
        for (int c2 = 0; c2 < 2; c2++) {
            const float* sp = Sp + c * 64 + c2 * 32;
            float4 a0 = *(const float4*)(sp);
            float4 a1 = *(const float4*)(sp + 4);
            bf16x8 af = packc4(a0, a1);
            int cb = c2 * 128 + bq * 32;
            f32x4 w00 = *(const f32x4*)(wb + j0 * 256 + (cb ^ sw0));
            f32x4 w01 = *(const f32x4*)(wb + j0 * 256 + ((cb + 16) ^ sw0));
            acc0 = __builtin_amdgcn_mfma_f32_16x16x32_bf16(af, packcv(w00, w01), acc0, 0, 0, 0);
            f32x4 w10 = *(const f32x4*)(wb + j1 * 256 + (cb ^ sw1));
            f32x4 w11 = *(const f32x4*)(wb + j1 * 256 + ((cb + 16) ^ sw1));
            acc1 = __builtin_amdgcn_mfma_f32_16x16x32_bf16(af, packcv(w10, w11), acc1, 0, 0, 0);
        }
        __syncthreads();
    }

    // epilogue: waves own disjoint j-tiles -> direct atomics (C: row=b, col=j)
    #pragma unroll
    for (int r = 0; r < 4; r++) {
        int b = bq * 4 + r;
        atomicAdd(&hraw[b * HID + (wave * 2) * 16 + lo], acc0[r]);
        atomicAdd(&hraw[b * HID + (wave * 2 + 1) * 16 + lo], acc1[r]);
    }
}

// ---------------- K4: bias+relu+fc2 head --------------------------------------
__global__ void k_head(const float* __restrict__ hraw, const float* __restrict__ b1,
                       const float* __restrict__ W2, const float* __restrict__ b2,
                       float* __restrict__ out) {
    __shared__ float hl[2048];
    int tid = threadIdx.x;
    for (int p = tid; p < 2048; p += 256) {
        float hv = hraw[p] + b1[p & 127];
        hl[p] = hv > 0.f ? hv : 0.f;
    }
    __syncthreads();
    if (tid < 160) {
        int b = tid / 10, c = tid - b * 10;
        float s = b2[c];
        for (int j = 0; j < 128; j++) s += hl[b * 128 + j] * W2[c * 128 + j];
        out[b * 10 + c] = s;
    }
}

extern "C" void kernel_launch(void* const* d_in, const int* in_sizes, int n_in,
                              void* d_out, int out_size, void* d_ws, size_t ws_size,
                              hipStream_t stream) {
    const float* x     = (const float*)d_in[0];
    const float* lambd = (const float*)d_in[1];
    const float* W1    = (const float*)d_in[2];
    const float* b1    = (const float*)d_in[3];
    const float* W2    = (const float*)d_in[4];
    const float* b2    = (const float*)d_in[5];
    float* out = (float*)d_out;
    float* ws  = (float*)d_ws;

    hipLaunchKernelGGL(k_prep,   dim3(16),         dim3(256), 0, stream, x, ws);
    hipLaunchKernelGGL(k_tables, dim3(1025),       dim3(256), 0, stream, lambd, ws);
    hipLaunchKernelGGL(k_spec,   dim3(16, 8, 16),  dim3(512), 0, stream, ws, out);
    hipLaunchKernelGGL(k_fc1,    dim3(512),        dim3(256), 0, stream,
                       out + 160, W1, ws + OFF_HRAW);
    hipLaunchKernelGGL(k_head,   dim3(1),          dim3(256), 0, stream,
                       ws + OFF_HRAW, b1, W2, b2, out);
}

// Round 13
// 202.378 us; speedup vs baseline: 1.1776x; 1.1549x over previous
//
#include <hip/hip_runtime.h>
#include <math.h>

#define NSIG   1023
#define BATCH  16
#define FT     1024          // F_BINS == T == 1024
#define KW     256           // truncated window taps, d in [-128, 127] (4 sigma)
#define RHALF  128
#define XPAD   1280          // 128 + 1023 + 127 (+2 pad)
#define HID    128

// ws layout (float offsets)
#define OFF_XCP  0u                       // 16*1280 = 20480
#define OFF_G    20480u                   // 256
#define OFF_HRAW 20736u                   // 2048  (fc1 accum, b-major: b*128+j)
#define OFF_TAB  22784u                   // bf16 hi/lo tables, 4 x 262144 u16
// u16 offsets within tab (f-major [f][256])
#define TAB_ECH  0u
#define TAB_ECL  262144u
#define TAB_ESH  524288u
#define TAB_ESL  786432u

typedef int    i32x4  __attribute__((ext_vector_type(4)));
typedef float  f32x4  __attribute__((ext_vector_type(4)));
typedef __bf16 bf16x8 __attribute__((ext_vector_type(8)));
typedef unsigned short u16;

static __device__ __forceinline__ unsigned bfbits(float v) {
    unsigned u = __builtin_bit_cast(unsigned, v);
    return (u + 0x7fffu + ((u >> 16) & 1u)) >> 16;   // RNE round to bf16
}

// ---------------- K0: per-batch mean removal into zero-padded buffer ----------
__global__ void k_prep(const float* __restrict__ x, float* __restrict__ ws) {
    int b = blockIdx.x;
    __shared__ float red[256];
    float s = 0.f;
    for (int i = threadIdx.x; i < NSIG; i += 256) s += x[b * NSIG + i];
    red[threadIdx.x] = s;
    __syncthreads();
    for (int o = 128; o > 0; o >>= 1) {
        if (threadIdx.x < o) red[threadIdx.x] += red[threadIdx.x + o];
        __syncthreads();
    }
    float mean = red[0] * (1.0f / NSIG);
    float* xcp = ws + OFF_XCP + b * XPAD;
    for (int i = threadIdx.x; i < XPAD; i += 256) {
        int n = i - RHALF;
        xcp[i] = (n >= 0 && n < NSIG) ? (x[b * NSIG + n] - mean) : 0.f;
    }
}

// ---------------- K1: hi/lo bf16 sincos tables, f-major [f][256] --------------
__global__ void k_tables(const float* __restrict__ lambd, float* __restrict__ ws) {
    int bid = blockIdx.x;
    if (bid == 1024) {
        float sigma = fabsf(lambd[0]);
        float inv2s2 = 0.5f / (sigma * sigma);
        for (int i = threadIdx.x; i < KW; i += 256) {
            float d = (float)(i - RHALF);
            ws[OFF_G + i] = expf(-d * d * inv2s2);
        }
        for (int i = threadIdx.x; i < 2048; i += 256) ws[OFF_HRAW + i] = 0.f;
        return;
    }
    int idx = bid * 256 + threadIdx.x;       // 0 .. 262143 = f*256 + k
    int f = idx >> 8, k = idx & 255;
    int d = k - RHALF;
    int p = f * d;                           // |p| <= 130944, fits int
    int m = p % 2046; if (m < 0) m += 2046;  // exact phase mod 2pi
    double ang = (double)m * (6.283185307179586476925286766559 / 2046.0);
    double sv, cv;
    sincos(ang, &sv, &cv);
    float cf = (float)cv, sf = (float)sv;
    u16* tab = (u16*)(ws + OFF_TAB);
    unsigned chb = bfbits(cf);
    float chf = __builtin_bit_cast(float, chb << 16);
    unsigned clb = bfbits(cf - chf);
    unsigned shb = bfbits(sf);
    float shf = __builtin_bit_cast(float, shb << 16);
    unsigned slb = bfbits(sf - shf);
    tab[TAB_ECH + idx] = (u16)chb;
    tab[TAB_ECL + idx] = (u16)clb;
    tab[TAB_ESH + idx] = (u16)shb;
    tab[TAB_ESL + idx] = (u16)slb;
}

// ---------------- K2: spectrogram MFMA, full-y-in-LDS, barrier-free loop ------
// (R6/R7 structure; split terms restored to Ah*Bh + Ah*Bl + Al*Bh)
__global__ __launch_bounds__(512, 4) void k_spec(const float* __restrict__ ws,
                                                 float* __restrict__ out) {
    __shared__ u16 yH[64 * 256];   // 32 KB, swizzled [t][256]
    __shared__ u16 yL[64 * 256];   // 32 KB
    int t0 = blockIdx.x * 64, f0 = blockIdx.y * 128, b = blockIdx.z;
    int tid = threadIdx.x;
    int wave = tid >> 6, lane = tid & 63;
    int lo = lane & 15, hi4 = lane >> 4;
    const u16* tab = (const u16*)(ws + OFF_TAB);
    const float* xcp = ws + OFF_XCP + b * XPAD;
    const float* gw  = ws + OFF_G;

    #pragma unroll
    for (int i = 0; i < 4; i++) {
        int idx = tid + i * 512;             // 0..2047
        int t = idx >> 5, kg = idx & 31;
        int k = kg * 8;
        const float* xp = xcp + t0 + t + k;
        float4 g0 = *(const float4*)&gw[k];
        float4 g1 = *(const float4*)&gw[k + 4];
        float yv[8];
        yv[0] = xp[0] * g0.x; yv[1] = xp[1] * g0.y;
        yv[2] = xp[2] * g0.z; yv[3] = xp[3] * g0.w;
        yv[4] = xp[4] * g1.x; yv[5] = xp[5] * g1.y;
        yv[6] = xp[6] * g1.z; yv[7] = xp[7] * g1.w;
        unsigned hb[8], lb[8];
        #pragma unroll
        for (int j = 0; j < 8; j++) {
            unsigned u = __builtin_bit_cast(unsigned, yv[j]);
            unsigned h = (u + 0x7fffu + ((u >> 16) & 1u)) & 0xffff0000u;
            float hf = __builtin_bit_cast(float, h);
            hb[j] = h >> 16;
            lb[j] = bfbits(yv[j] - hf);
        }
        i32x4 ph, pl;
        ph.x = (int)(hb[0] | (hb[1] << 16)); ph.y = (int)(hb[2] | (hb[3] << 16));
        ph.z = (int)(hb[4] | (hb[5] << 16)); ph.w = (int)(hb[6] | (hb[7] << 16));
        pl.x = (int)(lb[0] | (lb[1] << 16)); pl.y = (int)(lb[2] | (lb[3] << 16));
        pl.z = (int)(lb[4] | (lb[5] << 16)); pl.w = (int)(lb[6] | (lb[7] << 16));
        int wb = ((t * 512 + kg * 16) ^ ((t & 7) << 4));
        *(i32x4*)((char*)yH + wb) = ph;
        *(i32x4*)((char*)yL + wb) = pl;
    }
    __syncthreads();

    size_t arow = (size_t)(f0 + wave * 16 + lo) * 256 + hi4 * 8;
    const u16* pech = tab + TAB_ECH + arow;
    const u16* pecl = tab + TAB_ECL + arow;
    const u16* pesh = tab + TAB_ESH + arow;
    const u16* pesl = tab + TAB_ESL + arow;

    f32x4 reA[4], imA[4];
    #pragma unroll
    for (int i = 0; i < 4; i++) {
        reA[i] = (f32x4){0.f, 0.f, 0.f, 0.f};
        imA[i] = (f32x4){0.f, 0.f, 0.f, 0.f};
    }

    #pragma unroll 2
    for (int c = 0; c < 8; c++) {
        i32x4 ech = *(const i32x4*)(pech + c * 32);
        i32x4 ecl = *(const i32x4*)(pecl + c * 32);
        i32x4 esh = *(const i32x4*)(pesh + c * 32);
        i32x4 esl = *(const i32x4*)(pesl + c * 32);
        #pragma unroll
        for (int tt = 0; tt < 4; tt++) {
            int tr = tt * 16 + lo;
            int rb = ((tr * 512 + c * 64 + hi4 * 16) ^ ((tr & 7) << 4));
            i32x4 yh = *(const i32x4*)((const char*)yH + rb);
            i32x4 yl = *(const i32x4*)((const char*)yL + rb);
            asm("v_mfma_f32_16x16x32_bf16 %0, %1, %2, %0" : "+v"(reA[tt]) : "v"(ech), "v"(yh));
            asm("v_mfma_f32_16x16x32_bf16 %0, %1, %2, %0" : "+v"(imA[tt]) : "v"(esh), "v"(yh));
            asm("v_mfma_f32_16x16x32_bf16 %0, %1, %2, %0" : "+v"(reA[tt]) : "v"(ech), "v"(yl));
            asm("v_mfma_f32_16x16x32_bf16 %0, %1, %2, %0" : "+v"(imA[tt]) : "v"(esh), "v"(yl));
            asm("v_mfma_f32_16x16x32_bf16 %0, %1, %2, %0" : "+v"(reA[tt]) : "v"(ecl), "v"(yh));
            asm("v_mfma_f32_16x16x32_bf16 %0, %1, %2, %0" : "+v"(imA[tt]) : "v"(esl), "v"(yh));
        }
    }
    asm volatile("s_nop 7\n\ts_nop 7");   // MFMA->VALU read hazard guard

    float* dS = out + 160;
    #pragma unroll
    for (int tt = 0; tt < 4; tt++) {
        #pragma unroll
        for (int r = 0; r < 4; r++) {
            int f = f0 + wave * 16 + hi4 * 4 + r;
            float re = reA[tt][r], im = imA[tt][r];
            dS[((size_t)b << 20) + (size_t)f * 1024 + t0 + tt * 16 + lo] = re * re + im * im;
        }
    }
}

// ---------------- K3: fc1 — R11 staging engine + single S read ----------------
// h[b,j] = sum_i S[b,i]*W1[j,i]. 512 blocks x 4 waves; wave owns k-stripe
// ks = blockIdx*4+wave (512 k) and ALL 128 j. 32 chunks (s-outer, jt-inner):
// chunk (s, jt) stages W[jt*16..+16 rows][s*128..+128 k] f32 = 8 KB with
// 512 B-contiguous per-row fetches (R11-proven 5.9 TB/s), per-wave private
// double buffer, counted vmcnt(8), NO barriers. S fragments for sub-block s
// are packed once (af[4]) and reused across all 8 jt -> S read once grid-wide.
// Full unroll keeps acc[jt] statically indexed (rule #20).
static __device__ __forceinline__ bf16x8 packc4(float4 a, float4 b) {
    bf16x8 r;
    r[0] = (__bf16)a.x; r[1] = (__bf16)a.y; r[2] = (__bf16)a.z; r[3] = (__bf16)a.w;
    r[4] = (__bf16)b.x; r[5] = (__bf16)b.y; r[6] = (__bf16)b.z; r[7] = (__bf16)b.w;
    return r;
}
static __device__ __forceinline__ bf16x8 packcv(f32x4 a, f32x4 b) {
    bf16x8 r;
    r[0] = (__bf16)a.x; r[1] = (__bf16)a.y; r[2] = (__bf16)a.z; r[3] = (__bf16)a.w;
    r[4] = (__bf16)b.x; r[5] = (__bf16)b.y; r[6] = (__bf16)b.z; r[7] = (__bf16)b.w;
    return r;
}

// stage [16 rows][128 floats]: instr i covers rows {2i, 2i+1}, each row 512 B
// contiguous (swizzle-permuted in 16 B units). Byte-identical to R11's stageW.
static __device__ __forceinline__ void stageW(const float* base, float* dst,
                                              int rowLane, int colb0) {
    #pragma unroll
    for (int i = 0; i < 8; i++) {
        int sw = ((2 * (i & 3)) + rowLane) << 4;
        const float* src = base + (size_t)(2 * i + rowLane) * (1u << 20)
                         + ((colb0 ^ sw) >> 2);
        __builtin_amdgcn_global_load_lds(
            (const __attribute__((address_space(1))) void*)src,
            (__attribute__((address_space(3))) void*)((char*)dst + i * 1024),
            16, 0, 0);
    }
}

__global__ __launch_bounds__(256, 2) void k_fc1(const float* __restrict__ S,
                                                const float* __restrict__ W1,
                                                float* __restrict__ hraw) {
    __shared__ float Wl[4][2][2048];   // [wave][buf][8 KB] = 64 KB
    int tid = threadIdx.x;
    int wave = tid >> 6, lane = tid & 63;
    int bq = lane >> 4, lo = lane & 15;
    int ks = (blockIdx.x << 2) | wave;           // 0..2047 k-stripe
    size_t kb = (size_t)ks * 512;

    int rowLane = lane >> 5;                     // 0..1
    int colb0 = (lane & 31) << 4;                // 16 B col within 512 B row
    int sw = (lo & 7) << 4;

    const float* Sp = S + ((size_t)lo << 20) + kb + bq * 8;
    float* buf0 = &Wl[wave][0][0];
    float* buf1 = &Wl[wave][1][0];

    f32x4 acc[8];
    #pragma unroll
    for (int j = 0; j < 8; j++) acc[j] = (f32x4){0.f, 0.f, 0.f, 0.f};

    // prologue: stage chunk 0 (s=0, jt=0)
    stageW(W1 + kb, buf0, rowLane, colb0);

    bf16x8 af0, af1, af2, af3;

    #pragma unroll
    for (int c = 0; c < 32; c++) {
        const int s = c >> 3, jt = c & 7;
        float4 sA[8];
        if (jt == 0) {
            const float* sp = Sp + s * 128;
            #pragma unroll
            for (int q = 0; q < 4; q++) {
                sA[2 * q]     = *(const float4*)(sp + q * 32);
                sA[2 * q + 1] = *(const float4*)(sp + q * 32 + 4);
            }
        }
        if (c < 31) {
            const int cn = c + 1, sn = cn >> 3, jn = cn & 7;
            stageW(W1 + ((size_t)(jn * 16) << 20) + kb + sn * 128,
                   (c & 1) ? buf0 : buf1, rowLane, colb0);
            asm volatile("s_waitcnt vmcnt(8)" ::: "memory");
        } else {
            asm volatile("s_waitcnt vmcnt(0)" ::: "memory");
        }
        if (jt == 0) {
            af0 = packc4(sA[0], sA[1]);
            af1 = packc4(sA[2], sA[3]);
            af2 = packc4(sA[4], sA[5]);
            af3 = packc4(sA[6], sA[7]);
        }
        const char* wb = (const char*)((c & 1) ? buf1 : buf0);
        {
            int cb = 0 * 128 + bq * 32;
            f32x4 w0 = *(const f32x4*)(wb + lo * 512 + (cb ^ sw));
            f32x4 w1 = *(const f32x4*)(wb + lo * 512 + ((cb + 16) ^ sw));
            acc[jt] = __builtin_amdgcn_mfma_f32_16x16x32_bf16(af0, packcv(w0, w1), acc[jt], 0, 0, 0);
        }
        {
            int cb = 1 * 128 + bq * 32;
            f32x4 w0 = *(const f32x4*)(wb + lo * 512 + (cb ^ sw));
            f32x4 w1 = *(const f32x4*)(wb + lo * 512 + ((cb + 16) ^ sw));
            acc[jt] = __builtin_amdgcn_mfma_f32_16x16x32_bf16(af1, packcv(w0, w1), acc[jt], 0, 0, 0);
        }
        {
            int cb = 2 * 128 + bq * 32;
            f32x4 w0 = *(const f32x4*)(wb + lo * 512 + (cb ^ sw));
            f32x4 w1 = *(const f32x4*)(wb + lo * 512 + ((cb + 16) ^ sw));
            acc[jt] = __builtin_amdgcn_mfma_f32_16x16x32_bf16(af2, packcv(w0, w1), acc[jt], 0, 0, 0);
        }
        {
            int cb = 3 * 128 + bq * 32;
            f32x4 w0 = *(const f32x4*)(wb + lo * 512 + (cb ^ sw));
            f32x4 w1 = *(const f32x4*)(wb + lo * 512 + ((cb + 16) ^ sw));
            acc[jt] = __builtin_amdgcn_mfma_f32_16x16x32_bf16(af3, packcv(w0, w1), acc[jt], 0, 0, 0);
        }
    }

    // epilogue: per-wave partials -> LDS, cross-wave reduce, 2048 atomics/block
    float* red = &Wl[wave][0][0];
    #pragma unroll
    for (int jt = 0; jt < 8; jt++) {
        #pragma unroll
        for (int r = 0; r < 4; r++) {
            red[(bq * 4 + r) * 128 + jt * 16 + lo] = acc[jt][r];
        }
    }
    __syncthreads();
    for (int p = tid; p < 2048; p += 256) {
        float v = Wl[0][0][p] + Wl[1][0][p] + Wl[2][0][p] + Wl[3][0][p];
        atomicAdd(&hraw[p], v);
    }
}

// ---------------- K4: bias+relu+fc2 head --------------------------------------
__global__ void k_head(const float* __restrict__ hraw, const float* __restrict__ b1,
                       const float* __restrict__ W2, const float* __restrict__ b2,
                       float* __restrict__ out) {
    __shared__ float hl[2048];
    int tid = threadIdx.x;
    for (int p = tid; p < 2048; p += 256) {
        float hv = hraw[p] + b1[p & 127];
        hl[p] = hv > 0.f ? hv : 0.f;
    }
    __syncthreads();
    if (tid < 160) {
        int b = tid / 10, c = tid - b * 10;
        float s = b2[c];
        for (int j = 0; j < 128; j++) s += hl[b * 128 + j] * W2[c * 128 + j];
        out[b * 10 + c] = s;
    }
}

extern "C" void kernel_launch(void* const* d_in, const int* in_sizes, int n_in,
                              void* d_out, int out_size, void* d_ws, size_t ws_size,
                              hipStream_t stream) {
    const float* x     = (const float*)d_in[0];
    const float* lambd = (const float*)d_in[1];
    const float* W1    = (const float*)d_in[2];
    const float* b1    = (const float*)d_in[3];
    const float* W2    = (const float*)d_in[4];
    const float* b2    = (const float*)d_in[5];
    float* out = (float*)d_out;
    float* ws  = (float*)d_ws;

    hipLaunchKernelGGL(k_prep,   dim3(16),         dim3(256), 0, stream, x, ws);
    hipLaunchKernelGGL(k_tables, dim3(1025),       dim3(256), 0, stream, lambd, ws);
    hipLaunchKernelGGL(k_spec,   dim3(16, 8, 16),  dim3(512), 0, stream, ws, out);
    hipLaunchKernelGGL(k_fc1,    dim3(512),        dim3(256), 0, stream,
                       out + 160, W1, ws + OFF_HRAW);
    hipLaunchKernelGGL(k_head,   dim3(1),          dim3(256), 0, stream,
                       ws + OFF_HRAW, b1, W2, b2, out);
}

// Round 14
// 200.451 us; speedup vs baseline: 1.1890x; 1.0096x over previous
//
#include <hip/hip_runtime.h>
#include <math.h>

#define NSIG   1023
#define BATCH  16
#define FT     1024          // F_BINS == T == 1024
#define KW     256           // truncated window taps, d in [-128, 127] (4 sigma)
#define RHALF  128
#define XPAD   1280          // 128 + 1023 + 127 (+2 pad)
#define HID    128

// ws layout (float offsets)
#define OFF_XCP  0u                       // 16*1280 = 20480
#define OFF_G    20480u                   // 256
#define OFF_HRAW 20736u                   // 2048  (fc1 accum, b-major: b*128+j)
#define OFF_TAB  22784u                   // bf16 hi/lo tables, 4 x 262144 u16
// u16 offsets within tab (f-major [f][256])
#define TAB_ECH  0u
#define TAB_ECL  262144u
#define TAB_ESH  524288u
#define TAB_ESL  786432u

typedef int    i32x4  __attribute__((ext_vector_type(4)));
typedef float  f32x4  __attribute__((ext_vector_type(4)));
typedef __bf16 bf16x8 __attribute__((ext_vector_type(8)));
typedef unsigned short u16;

static __device__ __forceinline__ unsigned bfbits(float v) {
    unsigned u = __builtin_bit_cast(unsigned, v);
    return (u + 0x7fffu + ((u >> 16) & 1u)) >> 16;   // RNE round to bf16
}

// ---------------- K0: per-batch mean removal into zero-padded buffer ----------
__global__ void k_prep(const float* __restrict__ x, float* __restrict__ ws) {
    int b = blockIdx.x;
    __shared__ float red[256];
    float s = 0.f;
    for (int i = threadIdx.x; i < NSIG; i += 256) s += x[b * NSIG + i];
    red[threadIdx.x] = s;
    __syncthreads();
    for (int o = 128; o > 0; o >>= 1) {
        if (threadIdx.x < o) red[threadIdx.x] += red[threadIdx.x + o];
        __syncthreads();
    }
    float mean = red[0] * (1.0f / NSIG);
    float* xcp = ws + OFF_XCP + b * XPAD;
    for (int i = threadIdx.x; i < XPAD; i += 256) {
        int n = i - RHALF;
        xcp[i] = (n >= 0 && n < NSIG) ? (x[b * NSIG + n] - mean) : 0.f;
    }
}

// ---------------- K1: hi/lo bf16 sincos tables, f-major [f][256] --------------
__global__ void k_tables(const float* __restrict__ lambd, float* __restrict__ ws) {
    int bid = blockIdx.x;
    if (bid == 1024) {
        float sigma = fabsf(lambd[0]);
        float inv2s2 = 0.5f / (sigma * sigma);
        for (int i = threadIdx.x; i < KW; i += 256) {
            float d = (float)(i - RHALF);
            ws[OFF_G + i] = expf(-d * d * inv2s2);
        }
        for (int i = threadIdx.x; i < 2048; i += 256) ws[OFF_HRAW + i] = 0.f;
        return;
    }
    int idx = bid * 256 + threadIdx.x;       // 0 .. 262143 = f*256 + k
    int f = idx >> 8, k = idx & 255;
    int d = k - RHALF;
    int p = f * d;                           // |p| <= 130944, fits int
    int m = p % 2046; if (m < 0) m += 2046;  // exact phase mod 2pi
    double ang = (double)m * (6.283185307179586476925286766559 / 2046.0);
    double sv, cv;
    sincos(ang, &sv, &cv);
    float cf = (float)cv, sf = (float)sv;
    u16* tab = (u16*)(ws + OFF_TAB);
    unsigned chb = bfbits(cf);
    float chf = __builtin_bit_cast(float, chb << 16);
    unsigned clb = bfbits(cf - chf);
    unsigned shb = bfbits(sf);
    float shf = __builtin_bit_cast(float, shb << 16);
    unsigned slb = bfbits(sf - shf);
    tab[TAB_ECH + idx] = (u16)chb;
    tab[TAB_ECL + idx] = (u16)clb;
    tab[TAB_ESH + idx] = (u16)shb;
    tab[TAB_ESL + idx] = (u16)slb;
}

// ---------------- K2: spectrogram MFMA, full-y-in-LDS, barrier-free loop ------
// (unchanged from R13)
__global__ __launch_bounds__(512, 4) void k_spec(const float* __restrict__ ws,
                                                 float* __restrict__ out) {
    __shared__ u16 yH[64 * 256];   // 32 KB, swizzled [t][256]
    __shared__ u16 yL[64 * 256];   // 32 KB
    int t0 = blockIdx.x * 64, f0 = blockIdx.y * 128, b = blockIdx.z;
    int tid = threadIdx.x;
    int wave = tid >> 6, lane = tid & 63;
    int lo = lane & 15, hi4 = lane >> 4;
    const u16* tab = (const u16*)(ws + OFF_TAB);
    const float* xcp = ws + OFF_XCP + b * XPAD;
    const float* gw  = ws + OFF_G;

    #pragma unroll
    for (int i = 0; i < 4; i++) {
        int idx = tid + i * 512;             // 0..2047
        int t = idx >> 5, kg = idx & 31;
        int k = kg * 8;
        const float* xp = xcp + t0 + t + k;
        float4 g0 = *(const float4*)&gw[k];
        float4 g1 = *(const float4*)&gw[k + 4];
        float yv[8];
        yv[0] = xp[0] * g0.x; yv[1] = xp[1] * g0.y;
        yv[2] = xp[2] * g0.z; yv[3] = xp[3] * g0.w;
        yv[4] = xp[4] * g1.x; yv[5] = xp[5] * g1.y;
        yv[6] = xp[6] * g1.z; yv[7] = xp[7] * g1.w;
        unsigned hb[8], lb[8];
        #pragma unroll
        for (int j = 0; j < 8; j++) {
            unsigned u = __builtin_bit_cast(unsigned, yv[j]);
            unsigned h = (u + 0x7fffu + ((u >> 16) & 1u)) & 0xffff0000u;
            float hf = __builtin_bit_cast(float, h);
            hb[j] = h >> 16;
            lb[j] = bfbits(yv[j] - hf);
        }
        i32x4 ph, pl;
        ph.x = (int)(hb[0] | (hb[1] << 16)); ph.y = (int)(hb[2] | (hb[3] << 16));
        ph.z = (int)(hb[4] | (hb[5] << 16)); ph.w = (int)(hb[6] | (hb[7] << 16));
        pl.x = (int)(lb[0] | (lb[1] << 16)); pl.y = (int)(lb[2] | (lb[3] << 16));
        pl.z = (int)(lb[4] | (lb[5] << 16)); pl.w = (int)(lb[6] | (lb[7] << 16));
        int wb = ((t * 512 + kg * 16) ^ ((t & 7) << 4));
        *(i32x4*)((char*)yH + wb) = ph;
        *(i32x4*)((char*)yL + wb) = pl;
    }
    __syncthreads();

    size_t arow = (size_t)(f0 + wave * 16 + lo) * 256 + hi4 * 8;
    const u16* pech = tab + TAB_ECH + arow;
    const u16* pecl = tab + TAB_ECL + arow;
    const u16* pesh = tab + TAB_ESH + arow;
    const u16* pesl = tab + TAB_ESL + arow;

    f32x4 reA[4], imA[4];
    #pragma unroll
    for (int i = 0; i < 4; i++) {
        reA[i] = (f32x4){0.f, 0.f, 0.f, 0.f};
        imA[i] = (f32x4){0.f, 0.f, 0.f, 0.f};
    }

    #pragma unroll 2
    for (int c = 0; c < 8; c++) {
        i32x4 ech = *(const i32x4*)(pech + c * 32);
        i32x4 ecl = *(const i32x4*)(pecl + c * 32);
        i32x4 esh = *(const i32x4*)(pesh + c * 32);
        i32x4 esl = *(const i32x4*)(pesl + c * 32);
        #pragma unroll
        for (int tt = 0; tt < 4; tt++) {
            int tr = tt * 16 + lo;
            int rb = ((tr * 512 + c * 64 + hi4 * 16) ^ ((tr & 7) << 4));
            i32x4 yh = *(const i32x4*)((const char*)yH + rb);
            i32x4 yl = *(const i32x4*)((const char*)yL + rb);
            asm("v_mfma_f32_16x16x32_bf16 %0, %1, %2, %0" : "+v"(reA[tt]) : "v"(ech), "v"(yh));
            asm("v_mfma_f32_16x16x32_bf16 %0, %1, %2, %0" : "+v"(imA[tt]) : "v"(esh), "v"(yh));
            asm("v_mfma_f32_16x16x32_bf16 %0, %1, %2, %0" : "+v"(reA[tt]) : "v"(ech), "v"(yl));
            asm("v_mfma_f32_16x16x32_bf16 %0, %1, %2, %0" : "+v"(imA[tt]) : "v"(esh), "v"(yl));
            asm("v_mfma_f32_16x16x32_bf16 %0, %1, %2, %0" : "+v"(reA[tt]) : "v"(ecl), "v"(yh));
            asm("v_mfma_f32_16x16x32_bf16 %0, %1, %2, %0" : "+v"(imA[tt]) : "v"(esl), "v"(yh));
        }
    }
    asm volatile("s_nop 7\n\ts_nop 7");   // MFMA->VALU read hazard guard

    float* dS = out + 160;
    #pragma unroll
    for (int tt = 0; tt < 4; tt++) {
        #pragma unroll
        for (int r = 0; r < 4; r++) {
            int f = f0 + wave * 16 + hi4 * 4 + r;
            float re = reA[tt][r], im = imA[tt][r];
            dS[((size_t)b << 20) + (size_t)f * 1024 + t0 + tt * 16 + lo] = re * re + im * im;
        }
    }
}

// ---------------- K3: fc1 — page-hot staging (jt-outer) + S-in-registers ------
// h[b,j] = sum_i S[b,i]*W1[j,i]. 512 blocks x 4 waves; wave owns k-stripe
// ks = blockIdx*4+wave (512 k) and ALL 128 j. All S fragments pre-packed into
// af[4][4] (64 VGPR, static indexing via full unroll) -> S read once
// grid-wide. Chunk loop jt-OUTER / s-INNER: 4 consecutive chunks stay on the
// SAME 16 W1 rows walking columns 512 B-contiguously (R11's proven 5.9 TB/s
// page-hot pattern). Per-wave private double buffer, counted vmcnt(8), no
// barriers in the loop.
static __device__ __forceinline__ bf16x8 packc4(float4 a, float4 b) {
    bf16x8 r;
    r[0] = (__bf16)a.x; r[1] = (__bf16)a.y; r[2] = (__bf16)a.z; r[3] = (__bf16)a.w;
    r[4] = (__bf16)b.x; r[5] = (__bf16)b.y; r[6] = (__bf16)b.z; r[7] = (__bf16)b.w;
    return r;
}
static __device__ __forceinline__ bf16x8 packcv(f32x4 a, f32x4 b) {
    bf16x8 r;
    r[0] = (__bf16)a.x; r[1] = (__bf16)a.y; r[2] = (__bf16)a.z; r[3] = (__bf16)a.w;
    r[4] = (__bf16)b.x; r[5] = (__bf16)b.y; r[6] = (__bf16)b.z; r[7] = (__bf16)b.w;
    return r;
}

// stage [16 rows][128 floats]: instr i covers rows {2i, 2i+1}, each row 512 B
// contiguous (swizzle-permuted in 16 B units). Byte-identical to R11/R13.
static __device__ __forceinline__ void stageW(const float* base, float* dst,
                                              int rowLane, int colb0) {
    #pragma unroll
    for (int i = 0; i < 8; i++) {
        int sw = ((2 * (i & 3)) + rowLane) << 4;
        const float* src = base + (size_t)(2 * i + rowLane) * (1u << 20)
                         + ((colb0 ^ sw) >> 2);
        __builtin_amdgcn_global_load_lds(
            (const __attribute__((address_space(1))) void*)src,
            (__attribute__((address_space(3))) void*)((char*)dst + i * 1024),
            16, 0, 0);
    }
}

__global__ __launch_bounds__(256, 2) void k_fc1(const float* __restrict__ S,
                                                const float* __restrict__ W1,
                                                float* __restrict__ hraw) {
    __shared__ float Wl[4][2][2048];   // [wave][buf][8 KB] = 64 KB
    int tid = threadIdx.x;
    int wave = tid >> 6, lane = tid & 63;
    int bq = lane >> 4, lo = lane & 15;
    int ks = (blockIdx.x << 2) | wave;           // 0..2047 k-stripe
    size_t kb = (size_t)ks * 512;

    int rowLane = lane >> 5;                     // 0..1
    int colb0 = (lane & 31) << 4;                // 16 B col within 512 B row
    int sw = (lo & 7) << 4;

    const float* Sp = S + ((size_t)lo << 20) + kb + bq * 8;
    float* buf0 = &Wl[wave][0][0];
    float* buf1 = &Wl[wave][1][0];

    // ---- preload + pack ALL S for this stripe (read once grid-wide) ----
    bf16x8 af[4][4];
    #pragma unroll
    for (int s = 0; s < 4; s++) {
        #pragma unroll
        for (int q = 0; q < 4; q++) {
            float4 a0 = *(const float4*)(Sp + s * 128 + q * 32);
            float4 a1 = *(const float4*)(Sp + s * 128 + q * 32 + 4);
            af[s][q] = packc4(a0, a1);
        }
    }

    f32x4 acc[8];
    #pragma unroll
    for (int j = 0; j < 8; j++) acc[j] = (f32x4){0.f, 0.f, 0.f, 0.f};

    // prologue: stage chunk 0 (jt=0, s=0)
    stageW(W1 + kb, buf0, rowLane, colb0);

    #pragma unroll
    for (int c = 0; c < 32; c++) {
        const int jt = c >> 2, s = c & 3;
        if (c < 31) {
            const int cn = c + 1, jn = cn >> 2, sn = cn & 3;
            stageW(W1 + ((size_t)(jn * 16) << 20) + kb + sn * 128,
                   (c & 1) ? buf0 : buf1, rowLane, colb0);
            asm volatile("s_waitcnt vmcnt(8)" ::: "memory");
        } else {
            asm volatile("s_waitcnt vmcnt(0)" ::: "memory");
        }
        const char* wb = (const char*)((c & 1) ? buf1 : buf0);
        #pragma unroll
        for (int q = 0; q < 4; q++) {
            int cb = q * 128 + bq * 32;
            f32x4 w0 = *(const f32x4*)(wb + lo * 512 + (cb ^ sw));
            f32x4 w1 = *(const f32x4*)(wb + lo * 512 + ((cb + 16) ^ sw));
            acc[jt] = __builtin_amdgcn_mfma_f32_16x16x32_bf16(af[s][q], packcv(w0, w1),
                                                              acc[jt], 0, 0, 0);
        }
    }

    // epilogue: per-wave partials -> LDS, cross-wave reduce, 2048 atomics/block
    float* red = &Wl[wave][0][0];
    #pragma unroll
    for (int jt = 0; jt < 8; jt++) {
        #pragma unroll
        for (int r = 0; r < 4; r++) {
            red[(bq * 4 + r) * 128 + jt * 16 + lo] = acc[jt][r];
        }
    }
    __syncthreads();
    for (int p = tid; p < 2048; p += 256) {
        float v = Wl[0][0][p] + Wl[1][0][p] + Wl[2][0][p] + Wl[3][0][p];
        atomicAdd(&hraw[p], v);
    }
}

// ---------------- K4: bias+relu+fc2 head --------------------------------------
__global__ void k_head(const float* __restrict__ hraw, const float* __restrict__ b1,
                       const float* __restrict__ W2, const float* __restrict__ b2,
                       float* __restrict__ out) {
    __shared__ float hl[2048];
    int tid = threadIdx.x;
    for (int p = tid; p < 2048; p += 256) {
        float hv = hraw[p] + b1[p & 127];
        hl[p] = hv > 0.f ? hv : 0.f;
    }
    __syncthreads();
    if (tid < 160) {
        int b = tid / 10, c = tid - b * 10;
        float s = b2[c];
        for (int j = 0; j < 128; j++) s += hl[b * 128 + j] * W2[c * 128 + j];
        out[b * 10 + c] = s;
    }
}

extern "C" void kernel_launch(void* const* d_in, const int* in_sizes, int n_in,
                              void* d_out, int out_size, void* d_ws, size_t ws_size,
                              hipStream_t stream) {
    const float* x     = (const float*)d_in[0];
    const float* lambd = (const float*)d_in[1];
    const float* W1    = (const float*)d_in[2];
    const float* b1    = (const float*)d_in[3];
    const float* W2    = (const float*)d_in[4];
    const float* b2    = (const float*)d_in[5];
    float* out = (float*)d_out;
    float* ws  = (float*)d_ws;

    hipLaunchKernelGGL(k_prep,   dim3(16),         dim3(256), 0, stream, x, ws);
    hipLaunchKernelGGL(k_tables, dim3(1025),       dim3(256), 0, stream, lambd, ws);
    hipLaunchKernelGGL(k_spec,   dim3(16, 8, 16),  dim3(512), 0, stream, ws, out);
    hipLaunchKernelGGL(k_fc1,    dim3(512),        dim3(256), 0, stream,
                       out + 160, W1, ws + OFF_HRAW);
    hipLaunchKernelGGL(k_head,   dim3(1),          dim3(256), 0, stream,
                       ws + OFF_HRAW, b1, W2, b2, out);
}

// Round 15
// 198.216 us; speedup vs baseline: 1.2024x; 1.0113x over previous
//
#include <hip/hip_runtime.h>
#include <math.h>

#define NSIG   1023
#define BATCH  16
#define FT     1024          // F_BINS == T == 1024
#define KW     256           // truncated window taps, d in [-128, 127] (4 sigma)
#define RHALF  128
#define XPAD   1280          // 128 + 1023 + 127 (+2 pad)
#define HID    128

// ws layout (float offsets)
#define OFF_XCP  0u                       // 16*1280 = 20480
#define OFF_G    20480u                   // 256
#define OFF_HRAW 20736u                   // 2048  (fc1 accum, b-major: b*128+j)
#define OFF_TAB  22784u                   // bf16 hi/lo tables, 4 x 262144 u16
// u16 offsets within tab (f-major [f][256])
#define TAB_ECH  0u
#define TAB_ECL  262144u
#define TAB_ESH  524288u
#define TAB_ESL  786432u

typedef int    i32x4  __attribute__((ext_vector_type(4)));
typedef float  f32x4  __attribute__((ext_vector_type(4)));
typedef __bf16 bf16x8 __attribute__((ext_vector_type(8)));
typedef unsigned short u16;

static __device__ __forceinline__ unsigned bfbits(float v) {
    unsigned u = __builtin_bit_cast(unsigned, v);
    return (u + 0x7fffu + ((u >> 16) & 1u)) >> 16;   // RNE round to bf16
}

// ---------------- K0: per-batch mean removal into zero-padded buffer ----------
__global__ void k_prep(const float* __restrict__ x, float* __restrict__ ws) {
    int b = blockIdx.x;
    __shared__ float red[256];
    float s = 0.f;
    for (int i = threadIdx.x; i < NSIG; i += 256) s += x[b * NSIG + i];
    red[threadIdx.x] = s;
    __syncthreads();
    for (int o = 128; o > 0; o >>= 1) {
        if (threadIdx.x < o) red[threadIdx.x] += red[threadIdx.x + o];
        __syncthreads();
    }
    float mean = red[0] * (1.0f / NSIG);
    float* xcp = ws + OFF_XCP + b * XPAD;
    for (int i = threadIdx.x; i < XPAD; i += 256) {
        int n = i - RHALF;
        xcp[i] = (n >= 0 && n < NSIG) ? (x[b * NSIG + n] - mean) : 0.f;
    }
}

// ---------------- K1: hi/lo bf16 sincos tables, f-major [f][256] --------------
__global__ void k_tables(const float* __restrict__ lambd, float* __restrict__ ws) {
    int bid = blockIdx.x;
    if (bid == 1024) {
        float sigma = fabsf(lambd[0]);
        float inv2s2 = 0.5f / (sigma * sigma);
        for (int i = threadIdx.x; i < KW; i += 256) {
            float d = (float)(i - RHALF);
            ws[OFF_G + i] = expf(-d * d * inv2s2);
        }
        for (int i = threadIdx.x; i < 2048; i += 256) ws[OFF_HRAW + i] = 0.f;
        return;
    }
    int idx = bid * 256 + threadIdx.x;       // 0 .. 262143 = f*256 + k
    int f = idx >> 8, k = idx & 255;
    int d = k - RHALF;
    int p = f * d;                           // |p| <= 130944, fits int
    int m = p % 2046; if (m < 0) m += 2046;  // exact phase mod 2pi
    double ang = (double)m * (6.283185307179586476925286766559 / 2046.0);
    double sv, cv;
    sincos(ang, &sv, &cv);
    float cf = (float)cv, sf = (float)sv;
    u16* tab = (u16*)(ws + OFF_TAB);
    unsigned chb = bfbits(cf);
    float chf = __builtin_bit_cast(float, chb << 16);
    unsigned clb = bfbits(cf - chf);
    unsigned shb = bfbits(sf);
    float shf = __builtin_bit_cast(float, shb << 16);
    unsigned slb = bfbits(sf - shf);
    tab[TAB_ECH + idx] = (u16)chb;
    tab[TAB_ECL + idx] = (u16)clb;
    tab[TAB_ESH + idx] = (u16)shb;
    tab[TAB_ESL + idx] = (u16)slb;
}

// ---------------- K2: spectrogram MFMA, full-y-in-LDS, barrier-free loop ------
// (unchanged from R13/R14)
__global__ __launch_bounds__(512, 4) void k_spec(const float* __restrict__ ws,
                                                 float* __restrict__ out) {
    __shared__ u16 yH[64 * 256];   // 32 KB, swizzled [t][256]
    __shared__ u16 yL[64 * 256];   // 32 KB
    int t0 = blockIdx.x * 64, f0 = blockIdx.y * 128, b = blockIdx.z;
    int tid = threadIdx.x;
    int wave = tid >> 6, lane = tid & 63;
    int lo = lane & 15, hi4 = lane >> 4;
    const u16* tab = (const u16*)(ws + OFF_TAB);
    const float* xcp = ws + OFF_XCP + b * XPAD;
    const float* gw  = ws + OFF_G;

    #pragma unroll
    for (int i = 0; i < 4; i++) {
        int idx = tid + i * 512;             // 0..2047
        int t = idx >> 5, kg = idx & 31;
        int k = kg * 8;
        const float* xp = xcp + t0 + t + k;
        float4 g0 = *(const float4*)&gw[k];
        float4 g1 = *(const float4*)&gw[k + 4];
        float yv[8];
        yv[0] = xp[0] * g0.x; yv[1] = xp[1] * g0.y;
        yv[2] = xp[2] * g0.z; yv[3] = xp[3] * g0.w;
        yv[4] = xp[4] * g1.x; yv[5] = xp[5] * g1.y;
        yv[6] = xp[6] * g1.z; yv[7] = xp[7] * g1.w;
        unsigned hb[8], lb[8];
        #pragma unroll
        for (int j = 0; j < 8; j++) {
            unsigned u = __builtin_bit_cast(unsigned, yv[j]);
            unsigned h = (u + 0x7fffu + ((u >> 16) & 1u)) & 0xffff0000u;
            float hf = __builtin_bit_cast(float, h);
            hb[j] = h >> 16;
            lb[j] = bfbits(yv[j] - hf);
        }
        i32x4 ph, pl;
        ph.x = (int)(hb[0] | (hb[1] << 16)); ph.y = (int)(hb[2] | (hb[3] << 16));
        ph.z = (int)(hb[4] | (hb[5] << 16)); ph.w = (int)(hb[6] | (hb[7] << 16));
        pl.x = (int)(lb[0] | (lb[1] << 16)); pl.y = (int)(lb[2] | (lb[3] << 16));
        pl.z = (int)(lb[4] | (lb[5] << 16)); pl.w = (int)(lb[6] | (lb[7] << 16));
        int wb = ((t * 512 + kg * 16) ^ ((t & 7) << 4));
        *(i32x4*)((char*)yH + wb) = ph;
        *(i32x4*)((char*)yL + wb) = pl;
    }
    __syncthreads();

    size_t arow = (size_t)(f0 + wave * 16 + lo) * 256 + hi4 * 8;
    const u16* pech = tab + TAB_ECH + arow;
    const u16* pecl = tab + TAB_ECL + arow;
    const u16* pesh = tab + TAB_ESH + arow;
    const u16* pesl = tab + TAB_ESL + arow;

    f32x4 reA[4], imA[4];
    #pragma unroll
    for (int i = 0; i < 4; i++) {
        reA[i] = (f32x4){0.f, 0.f, 0.f, 0.f};
        imA[i] = (f32x4){0.f, 0.f, 0.f, 0.f};
    }

    #pragma unroll 2
    for (int c = 0; c < 8; c++) {
        i32x4 ech = *(const i32x4*)(pech + c * 32);
        i32x4 ecl = *(const i32x4*)(pecl + c * 32);
        i32x4 esh = *(const i32x4*)(pesh + c * 32);
        i32x4 esl = *(const i32x4*)(pesl + c * 32);
        #pragma unroll
        for (int tt = 0; tt < 4; tt++) {
            int tr = tt * 16 + lo;
            int rb = ((tr * 512 + c * 64 + hi4 * 16) ^ ((tr & 7) << 4));
            i32x4 yh = *(const i32x4*)((const char*)yH + rb);
            i32x4 yl = *(const i32x4*)((const char*)yL + rb);
            asm("v_mfma_f32_16x16x32_bf16 %0, %1, %2, %0" : "+v"(reA[tt]) : "v"(ech), "v"(yh));
            asm("v_mfma_f32_16x16x32_bf16 %0, %1, %2, %0" : "+v"(imA[tt]) : "v"(esh), "v"(yh));
            asm("v_mfma_f32_16x16x32_bf16 %0, %1, %2, %0" : "+v"(reA[tt]) : "v"(ech), "v"(yl));
            asm("v_mfma_f32_16x16x32_bf16 %0, %1, %2, %0" : "+v"(imA[tt]) : "v"(esh), "v"(yl));
            asm("v_mfma_f32_16x16x32_bf16 %0, %1, %2, %0" : "+v"(reA[tt]) : "v"(ecl), "v"(yh));
            asm("v_mfma_f32_16x16x32_bf16 %0, %1, %2, %0" : "+v"(imA[tt]) : "v"(esl), "v"(yh));
        }
    }
    asm volatile("s_nop 7\n\ts_nop 7");   // MFMA->VALU read hazard guard

    float* dS = out + 160;
    #pragma unroll
    for (int tt = 0; tt < 4; tt++) {
        #pragma unroll
        for (int r = 0; r < 4; r++) {
            int f = f0 + wave * 16 + hi4 * 4 + r;
            float re = reA[tt][r], im = imA[tt][r];
            dS[((size_t)b << 20) + (size_t)f * 1024 + t0 + tt * 16 + lo] = re * re + im * im;
        }
    }
}

// ---------------- K3: fc1 — whole-row 1 KB staging runs -----------------------
// h[b,j] = sum_i S[b,i]*W1[j,i]. 512 blocks x 4 waves; wave owns k-stripe
// ks = blockIdx*4+wave (512 k) and ALL 128 j. Chunk = [16 rows][256 k] f32 =
// 16 KB staged as 16 instructions, each one FULL 1 KB row run (64 lanes on one
// contiguous 1 KB, 16B granules XOR-permuted by ((row&7)<<4) so the LDS read
// is at the b128 bank floor). Consecutive s-chunks continue each row
// contiguously -> long DRAM runs. Per-wave private 2x16 KB dbuf (128 KB/block,
// 1 block/CU, 4 waves/CU), counted vmcnt(16), NO barriers in the loop. S
// pre-packed into af[4][4] registers -> S read once grid-wide.
static __device__ __forceinline__ bf16x8 packc4(float4 a, float4 b) {
    bf16x8 r;
    r[0] = (__bf16)a.x; r[1] = (__bf16)a.y; r[2] = (__bf16)a.z; r[3] = (__bf16)a.w;
    r[4] = (__bf16)b.x; r[5] = (__bf16)b.y; r[6] = (__bf16)b.z; r[7] = (__bf16)b.w;
    return r;
}
static __device__ __forceinline__ bf16x8 packcv(f32x4 a, f32x4 b) {
    bf16x8 r;
    r[0] = (__bf16)a.x; r[1] = (__bf16)a.y; r[2] = (__bf16)a.z; r[3] = (__bf16)a.w;
    r[4] = (__bf16)b.x; r[5] = (__bf16)b.y; r[6] = (__bf16)b.z; r[7] = (__bf16)b.w;
    return r;
}

// stage [16 rows][256 floats]: instr i reads row i's 1 KB contiguous run.
// base = W1 + jt*16 rows + kb + s*256. laneByte = lane*16.
static __device__ __forceinline__ void stageC(const float* base, float* dst, int laneByte) {
    #pragma unroll
    for (int i = 0; i < 16; i++) {
        const float* src = base + ((size_t)i << 20)
                         + ((laneByte ^ ((i & 7) << 4)) >> 2);
        __builtin_amdgcn_global_load_lds(
            (const __attribute__((address_space(1))) void*)src,
            (__attribute__((address_space(3))) void*)((char*)dst + i * 1024),
            16, 0, 0);
    }
}

__global__ __launch_bounds__(256, 1) void k_fc1(const float* __restrict__ S,
                                                const float* __restrict__ W1,
                                                float* __restrict__ hraw) {
    __shared__ float Wl[4][2][4096];   // [wave][buf][16 KB] = 128 KB
    int tid = threadIdx.x;
    int wave = tid >> 6, lane = tid & 63;
    int bq = lane >> 4, lo = lane & 15;
    int ks = (blockIdx.x << 2) | wave;           // 0..2047 k-stripe
    size_t kb = (size_t)ks * 512;

    int laneByte = lane << 4;                    // 16 B per lane within 1 KB row
    int sw = (lo & 7) << 4;

    const float* Sp = S + ((size_t)lo << 20) + kb + bq * 8;
    float* buf0 = &Wl[wave][0][0];
    float* buf1 = &Wl[wave][1][0];

    // prologue: stage chunk 0 (jt=0, s=0) first so S waits don't stall it
    stageC(W1 + kb, buf0, laneByte);

    // ---- preload + pack ALL S for this stripe (read once grid-wide) ----
    bf16x8 af[4][4];
    #pragma unroll
    for (int s = 0; s < 4; s++) {
        #pragma unroll
        for (int q = 0; q < 4; q++) {
            float4 a0 = *(const float4*)(Sp + s * 128 + q * 32);
            float4 a1 = *(const float4*)(Sp + s * 128 + q * 32 + 4);
            af[s][q] = packc4(a0, a1);
        }
    }

    f32x4 acc[8];
    #pragma unroll
    for (int j = 0; j < 8; j++) acc[j] = (f32x4){0.f, 0.f, 0.f, 0.f};

    // 16 chunks: jt-outer (c>>1), s-half inner (c&1). Rows stay page-hot and
    // each row's two 1 KB fetches are address-contiguous.
    #pragma unroll
    for (int c = 0; c < 16; c++) {
        const int jt = c >> 1, sh = c & 1;
        if (c < 15) {
            const int cn = c + 1, jn = cn >> 1, sn = cn & 1;
            stageC(W1 + ((size_t)(jn * 16) << 20) + kb + sn * 256,
                   (c & 1) ? buf0 : buf1, laneByte);
            asm volatile("s_waitcnt vmcnt(16)" ::: "memory");
        } else {
            asm volatile("s_waitcnt vmcnt(0)" ::: "memory");
        }
        const char* wb = (const char*)((c & 1) ? buf1 : buf0);
        #pragma unroll
        for (int q = 0; q < 8; q++) {
            const int ki = sh * 8 + q;           // 32-k step within stripe
            int cb = q * 128 + bq * 32;
            f32x4 w0 = *(const f32x4*)(wb + lo * 1024 + (cb ^ sw));
            f32x4 w1 = *(const f32x4*)(wb + lo * 1024 + ((cb + 16) ^ sw));
            acc[jt] = __builtin_amdgcn_mfma_f32_16x16x32_bf16(af[ki >> 2][ki & 3],
                                                              packcv(w0, w1),
                                                              acc[jt], 0, 0, 0);
        }
    }

    // epilogue: per-wave partials -> LDS, cross-wave reduce, 2048 atomics/block
    float* red = &Wl[wave][0][0];
    #pragma unroll
    for (int jt = 0; jt < 8; jt++) {
        #pragma unroll
        for (int r = 0; r < 4; r++) {
            red[(bq * 4 + r) * 128 + jt * 16 + lo] = acc[jt][r];
        }
    }
    __syncthreads();
    for (int p = tid; p < 2048; p += 256) {
        float v = Wl[0][0][p] + Wl[1][0][p] + Wl[2][0][p] + Wl[3][0][p];
        atomicAdd(&hraw[p], v);
    }
}

// ---------------- K4: bias+relu+fc2 head --------------------------------------
__global__ void k_head(const float* __restrict__ hraw, const float* __restrict__ b1,
                       const float* __restrict__ W2, const float* __restrict__ b2,
                       float* __restrict__ out) {
    __shared__ float hl[2048];
    int tid = threadIdx.x;
    for (int p = tid; p < 2048; p += 256) {
        float hv = hraw[p] + b1[p & 127];
        hl[p] = hv > 0.f ? hv : 0.f;
    }
    __syncthreads();
    if (tid < 160) {
        int b = tid / 10, c = tid - b * 10;
        float s = b2[c];
        for (int j = 0; j < 128; j++) s += hl[b * 128 + j] * W2[c * 128 + j];
        out[b * 10 + c] = s;
    }
}

extern "C" void kernel_launch(void* const* d_in, const int* in_sizes, int n_in,
                              void* d_out, int out_size, void* d_ws, size_t ws_size,
                              hipStream_t stream) {
    const float* x     = (const float*)d_in[0];
    const float* lambd = (const float*)d_in[1];
    const float* W1    = (const float*)d_in[2];
    const float* b1    = (const float*)d_in[3];
    const float* W2    = (const float*)d_in[4];
    const float* b2    = (const float*)d_in[5];
    float* out = (float*)d_out;
    float* ws  = (float*)d_ws;

    hipLaunchKernelGGL(k_prep,   dim3(16),         dim3(256), 0, stream, x, ws);
    hipLaunchKernelGGL(k_tables, dim3(1025),       dim3(256), 0, stream, lambd, ws);
    hipLaunchKernelGGL(k_spec,   dim3(16, 8, 16),  dim3(512), 0, stream, ws, out);
    hipLaunchKernelGGL(k_fc1,    dim3(512),        dim3(256), 0, stream,
                       out + 160, W1, ws + OFF_HRAW);
    hipLaunchKernelGGL(k_head,   dim3(1),          dim3(256), 0, stream,
                       ws + OFF_HRAW, b1, W2, b2, out);
}